// Round 4
// baseline (389.199 us; speedup 1.0000x reference)
//
#include <hip/hip_runtime.h>
#include <math.h>

// BlockDiagAttention via split-bf16 MFMA (hi+lo, 3-term products ~= fp32).
// R4: persistent WGs (grid=1024), each handles a contiguous chunk of 4-5
// 64x64 diagonal blocks with one-block-ahead register prefetch (T14):
// Q/K(i+1) loads issue under QK^T/softmax of block i; V(i+1) under PV.
#define STRH 72
#define NWG 1024

typedef __attribute__((ext_vector_type(8))) short short8;
typedef __attribute__((ext_vector_type(4))) float f32x4;
typedef __attribute__((ext_vector_type(4))) short short4v;

// fp32 -> (bf16 hi rne, bf16 lo of residual)
__device__ __forceinline__ void split2(float x, unsigned short& h, unsigned short& l) {
  unsigned u = __float_as_uint(x);
  unsigned hb = (u + 0x7FFFu + ((u >> 16) & 1u)) & 0xFFFF0000u;
  h = (unsigned short)(hb >> 16);
  float r = x - __uint_as_float(hb);
  unsigned v = __float_as_uint(r);
  l = (unsigned short)((v + 0x7FFFu + ((v >> 16) & 1u)) >> 16);
}

__global__ __launch_bounds__(256, 4) void bda_kernel(
    const float* __restrict__ qg,
    const float* __restrict__ kg,
    const float* __restrict__ vg,
    float* __restrict__ og,
    int N, int nblk, int rem, int gtot) {
  __shared__ unsigned short Ah[64 * STRH];  // Q hi -> P hi
  __shared__ unsigned short Al[64 * STRH];  // Q lo -> P lo
  __shared__ unsigned short Bh[64 * STRH];  // K hi -> Vt hi
  __shared__ unsigned short Bl[64 * STRH];  // K lo -> Vt lo

  const int wg = blockIdx.x;
  const int g0 = (wg * gtot) >> 10;        // contiguous chunk [g0,g1)
  const int g1 = ((wg + 1) * gtot) >> 10;

  const int t    = threadIdx.x;
  const int lane = t & 63;
  const int w    = t >> 6;

  const int colb  = lane & 15;
  const int kofs  = (lane >> 4) * 8;
  const int arow  = 16 * w + colb;         // A-frag row (Q/P)
  const int rquad = (lane >> 4) * 4;
  const int vd  = lane;                    // V gather: d = lane
  const int vkb = w * 16;                  // V gather: k range per wave

  // ---- prologue: load block g0 into registers ----
  float4 qv[4], kv[4];
  float  vr[16];
  {
    const int blk = g0 % nblk;
    const int nr  = (blk == nblk - 1 && rem != 0) ? rem : 64;
    const size_t b = ((size_t)(g0 / nblk) * (size_t)N + (size_t)blk * 64) * 64;
#pragma unroll
    for (int rnd = 0; rnd < 4; ++rnd) {
      const int e = (t << 2) + (rnd << 10);
      const int row = e >> 6;
      qv[rnd] = make_float4(0.f, 0.f, 0.f, 0.f);
      kv[rnd] = qv[rnd];
      if (row < nr) {
        qv[rnd] = *(const float4*)(qg + b + e);
        kv[rnd] = *(const float4*)(kg + b + e);
      }
    }
#pragma unroll
    for (int i = 0; i < 16; ++i) {
      const int k = vkb + i;
      vr[i] = (k < nr) ? vg[b + (size_t)k * 64 + vd] : 0.f;
    }
  }

  for (int g = g0; g < g1; ++g) {
    const int blk = g % nblk;
    const int nrows = (blk == nblk - 1 && rem != 0) ? rem : 64;
    const size_t base = ((size_t)(g / nblk) * (size_t)N + (size_t)blk * 64) * 64;

    const bool more = (g + 1 < g1);
    int nnr = 64;
    size_t nbase = 0;
    if (more) {
      const int nb = (g + 1) % nblk;
      nnr   = (nb == nblk - 1 && rem != 0) ? rem : 64;
      nbase = ((size_t)((g + 1) / nblk) * (size_t)N + (size_t)nb * 64) * 64;
    }

    // ---- split+write Q,K (from regs) ----
#pragma unroll
    for (int rnd = 0; rnd < 4; ++rnd) {
      const int e = (t << 2) + (rnd << 10);
      const int row = e >> 6, col = e & 63;
      unsigned short qh[4], ql[4], kh[4], kl[4];
      split2(qv[rnd].x, qh[0], ql[0]); split2(qv[rnd].y, qh[1], ql[1]);
      split2(qv[rnd].z, qh[2], ql[2]); split2(qv[rnd].w, qh[3], ql[3]);
      split2(kv[rnd].x, kh[0], kl[0]); split2(kv[rnd].y, kh[1], kl[1]);
      split2(kv[rnd].z, kh[2], kl[2]); split2(kv[rnd].w, kh[3], kl[3]);
      const int a = row * STRH + col;
      *(short4v*)&Ah[a] = (short4v){(short)qh[0], (short)qh[1], (short)qh[2], (short)qh[3]};
      *(short4v*)&Al[a] = (short4v){(short)ql[0], (short)ql[1], (short)ql[2], (short)ql[3]};
      *(short4v*)&Bh[a] = (short4v){(short)kh[0], (short)kh[1], (short)kh[2], (short)kh[3]};
      *(short4v*)&Bl[a] = (short4v){(short)kl[0], (short)kl[1], (short)kl[2], (short)kl[3]};
    }

    // ---- prefetch Q,K of block g+1 (latency hides under QK^T+softmax) ----
    float4 qn[4], kn[4];
#pragma unroll
    for (int rnd = 0; rnd < 4; ++rnd) {
      const int e = (t << 2) + (rnd << 10);
      const int row = e >> 6;
      qn[rnd] = make_float4(0.f, 0.f, 0.f, 0.f);
      kn[rnd] = qn[rnd];
      if (more && row < nnr) {
        qn[rnd] = *(const float4*)(qg + nbase + e);
        kn[rnd] = *(const float4*)(kg + nbase + e);
      }
    }

    __syncthreads();  // Q,K staged

    // ---- S = Q K^T (3-term split MFMA), wave w -> rows 16w..16w+15 ----
    f32x4 acc[4];
#pragma unroll
    for (int i = 0; i < 4; ++i) acc[i] = (f32x4){0.f, 0.f, 0.f, 0.f};
#pragma unroll
    for (int ks = 0; ks < 2; ++ks) {
      const int kb = ks * 32 + kofs;
      const short8 ah = *(const short8*)&Ah[arow * STRH + kb];
      const short8 al = *(const short8*)&Al[arow * STRH + kb];
#pragma unroll
      for (int nt = 0; nt < 4; ++nt) {
        const int brow = 16 * nt + colb;
        const short8 bhv = *(const short8*)&Bh[brow * STRH + kb];
        const short8 blv = *(const short8*)&Bl[brow * STRH + kb];
        acc[nt] = __builtin_amdgcn_mfma_f32_16x16x32_bf16(al, bhv, acc[nt], 0, 0, 0);
        acc[nt] = __builtin_amdgcn_mfma_f32_16x16x32_bf16(ah, blv, acc[nt], 0, 0, 0);
        acc[nt] = __builtin_amdgcn_mfma_f32_16x16x32_bf16(ah, bhv, acc[nt], 0, 0, 0);
      }
    }

    // ---- wave-local softmax; P -> split bf16 into Ah/Al (own rows only) ----
#pragma unroll
    for (int r = 0; r < 4; ++r) {
      const int grow = 16 * w + rquad + r;
      float s[4];
#pragma unroll
      for (int nt = 0; nt < 4; ++nt) {
        const int col = 16 * nt + colb;
        s[nt] = (col < nrows) ? acc[nt][r] * 0.125f : -1e30f;
      }
      float m = fmaxf(fmaxf(s[0], s[1]), fmaxf(s[2], s[3]));
      m = fmaxf(m, __shfl_xor(m, 1));
      m = fmaxf(m, __shfl_xor(m, 2));
      m = fmaxf(m, __shfl_xor(m, 4));
      m = fmaxf(m, __shfl_xor(m, 8));
      float p[4];
      float lsum = 0.f;
#pragma unroll
      for (int nt = 0; nt < 4; ++nt) {
        p[nt] = __expf(s[nt] - m);
        lsum += p[nt];
      }
      lsum += __shfl_xor(lsum, 1);
      lsum += __shfl_xor(lsum, 2);
      lsum += __shfl_xor(lsum, 4);
      lsum += __shfl_xor(lsum, 8);
      const float inv = 1.f / lsum;
#pragma unroll
      for (int nt = 0; nt < 4; ++nt) {
        unsigned short hh, ll;
        split2(p[nt] * inv, hh, ll);
        Ah[grow * STRH + 16 * nt + colb] = hh;
        Al[grow * STRH + 16 * nt + colb] = ll;
      }
    }

    __syncthreads();  // all waves done with K frags; Bh/Bl -> Vt

    // ---- stage V transposed (from regs), split hi/lo ----
#pragma unroll
    for (int c = 0; c < 4; ++c) {
      unsigned short h4[4], l4[4];
#pragma unroll
      for (int i = 0; i < 4; ++i) split2(vr[4 * c + i], h4[i], l4[i]);
      const int a = vd * STRH + vkb + 4 * c;
      *(short4v*)&Bh[a] = (short4v){(short)h4[0], (short)h4[1], (short)h4[2], (short)h4[3]};
      *(short4v*)&Bl[a] = (short4v){(short)l4[0], (short)l4[1], (short)l4[2], (short)l4[3]};
    }

    // ---- prefetch V of block g+1 (latency hides under PV) ----
    float vn[16];
#pragma unroll
    for (int i = 0; i < 16; ++i) {
      const int k = vkb + i;
      vn[i] = (more && k < nnr) ? vg[nbase + (size_t)k * 64 + vd] : 0.f;
    }

    __syncthreads();  // Vt staged

    // ---- O = P V (3-term split MFMA) ----
    f32x4 oacc[4];
#pragma unroll
    for (int i = 0; i < 4; ++i) oacc[i] = (f32x4){0.f, 0.f, 0.f, 0.f};
#pragma unroll
    for (int ks = 0; ks < 2; ++ks) {
      const int kb = ks * 32 + kofs;
      const short8 ph = *(const short8*)&Ah[arow * STRH + kb];
      const short8 pl = *(const short8*)&Al[arow * STRH + kb];
#pragma unroll
      for (int nt = 0; nt < 4; ++nt) {
        const int vrow = 16 * nt + colb;
        const short8 vh = *(const short8*)&Bh[vrow * STRH + kb];
        const short8 vl = *(const short8*)&Bl[vrow * STRH + kb];
        oacc[nt] = __builtin_amdgcn_mfma_f32_16x16x32_bf16(pl, vh, oacc[nt], 0, 0, 0);
        oacc[nt] = __builtin_amdgcn_mfma_f32_16x16x32_bf16(ph, vl, oacc[nt], 0, 0, 0);
        oacc[nt] = __builtin_amdgcn_mfma_f32_16x16x32_bf16(ph, vh, oacc[nt], 0, 0, 0);
      }
    }

    // ---- store (C/D: row=(lane>>4)*4+reg, col=lane&15) ----
#pragma unroll
    for (int nt = 0; nt < 4; ++nt) {
#pragma unroll
      for (int r = 0; r < 4; ++r) {
        const int row = 16 * w + rquad + r;
        if (row < nrows) {
          og[base + (size_t)row * 64 + 16 * nt + colb] = oacc[nt][r];
        }
      }
    }

    // ---- rotate prefetched regs; fence LDS reuse for next iteration ----
    if (more) {
#pragma unroll
      for (int i = 0; i < 4; ++i) { qv[i] = qn[i]; kv[i] = kn[i]; }
#pragma unroll
      for (int i = 0; i < 16; ++i) vr[i] = vn[i];
      __syncthreads();  // PV reads of Ah/Al/Bh/Bl done before overwrite
    }
  }
}

extern "C" void kernel_launch(void* const* d_in, const int* in_sizes, int n_in,
                              void* d_out, int out_size, void* d_ws, size_t ws_size,
                              hipStream_t stream) {
  const float* q = (const float*)d_in[0];
  const float* k = (const float*)d_in[1];
  const float* v = (const float*)d_in[2];
  float* o = (float*)d_out;

  const int N    = 4128;
  const int BH   = in_sizes[0] / (N * 64);  // 64
  const int nblk = (N + 63) / 64;           // 65
  const int rem  = N & 63;                  // 32
  const int gtot = BH * nblk;               // 4160 total blocks

  bda_kernel<<<dim3(NWG), dim3(256), 0, stream>>>(q, k, v, o, N, nblk, rem, gtot);
}

// Round 5
// 226.942 us; speedup vs baseline: 1.7150x; 1.7150x over previous
//
#include <hip/hip_runtime.h>
#include <math.h>

// BlockDiagAttention, R5: barrier-free split-bf16 MFMA.
// One 256-thread WG (4 waves) per 64x64 diagonal block. Q,K are loaded
// DIRECTLY from global in MFMA fragment layout (row=lane&15, 8 contiguous
// floats at k=(lane>>4)*8) -> no staging LDS, no __syncthreads anywhere.
// V is gathered transposed (8 stride-256B dwords per fragment; L1-resident,
// 4 waves share the 16KB tile). P redistribution (C-layout -> A-frag) is
// intra-wave, via wave-private LDS rows (compiler lgkmcnt only).
#define STRH 72  // P row stride in shorts

typedef __attribute__((ext_vector_type(8))) short short8;
typedef __attribute__((ext_vector_type(4))) float f32x4;

// fp32 -> (bf16 hi RNE, bf16 lo = RNE(residual)); 3-term MFMA ~= fp32
__device__ __forceinline__ void split2(float x, unsigned short& h, unsigned short& l) {
  unsigned u = __float_as_uint(x);
  unsigned hb = (u + 0x7FFFu + ((u >> 16) & 1u)) & 0xFFFF0000u;
  h = (unsigned short)(hb >> 16);
  float r = x - __uint_as_float(hb);
  unsigned v = __float_as_uint(r);
  l = (unsigned short)((v + 0x7FFFu + ((v >> 16) & 1u)) >> 16);
}

__device__ __forceinline__ void split8(const float* x, short8& h, short8& l) {
  unsigned short hh[8], ll[8];
#pragma unroll
  for (int i = 0; i < 8; ++i) split2(x[i], hh[i], ll[i]);
  h = (short8){(short)hh[0], (short)hh[1], (short)hh[2], (short)hh[3],
               (short)hh[4], (short)hh[5], (short)hh[6], (short)hh[7]};
  l = (short8){(short)ll[0], (short)ll[1], (short)ll[2], (short)ll[3],
               (short)ll[4], (short)ll[5], (short)ll[6], (short)ll[7]};
}

__global__ __launch_bounds__(256, 4) void bda_kernel(
    const float* __restrict__ qg,
    const float* __restrict__ kg,
    const float* __restrict__ vg,
    float* __restrict__ og,
    int N, int nblk, int rem) {
  __shared__ unsigned short Ph[64 * STRH];
  __shared__ unsigned short Pl[64 * STRH];

  const int wg  = blockIdx.x;
  const int blk = wg % nblk;
  const int bh  = wg / nblk;
  const int nrows = (blk == nblk - 1 && rem != 0) ? rem : 64;
  const size_t base = ((size_t)bh * (size_t)N + (size_t)blk * 64) * 64;

  const int t    = threadIdx.x;
  const int lane = t & 63;
  const int w    = t >> 6;

  const int colb  = lane & 15;
  const int grp   = lane >> 4;
  const int kofs  = grp * 8;
  const int rquad = grp * 4;
  const int arow  = 16 * w + colb;          // this lane's Q/O row
  const bool wvalid = (16 * w) < nrows;     // wave has live rows

  // ---- Q fragments: direct global load in A-frag layout ----
  short8 qh[2], ql[2];
#pragma unroll
  for (int ks = 0; ks < 2; ++ks) {
    float qf[8];
    if (wvalid) {
      const float* p = qg + base + (size_t)arow * 64 + ks * 32 + kofs;
      *(float4*)&qf[0] = *(const float4*)p;
      *(float4*)&qf[4] = *(const float4*)(p + 4);
    } else {
#pragma unroll
      for (int i = 0; i < 8; ++i) qf[i] = 0.f;
    }
    split8(qf, qh[ks], ql[ks]);
  }

  // ---- S = Q K^T: K fragments direct from global, 3-term split MFMA ----
  f32x4 acc[4];
#pragma unroll
  for (int i = 0; i < 4; ++i) acc[i] = (f32x4){0.f, 0.f, 0.f, 0.f};
#pragma unroll
  for (int nt = 0; nt < 4; ++nt) {
    if (16 * nt < nrows) {  // wave-uniform; K rows 16nt..16nt+15 exist
      const float* kp = kg + base + (size_t)(16 * nt + colb) * 64 + kofs;
#pragma unroll
      for (int ks = 0; ks < 2; ++ks) {
        float kf[8];
        *(float4*)&kf[0] = *(const float4*)(kp + ks * 32);
        *(float4*)&kf[4] = *(const float4*)(kp + ks * 32 + 4);
        short8 kh, kl;
        split8(kf, kh, kl);
        acc[nt] = __builtin_amdgcn_mfma_f32_16x16x32_bf16(ql[ks], kh, acc[nt], 0, 0, 0);
        acc[nt] = __builtin_amdgcn_mfma_f32_16x16x32_bf16(qh[ks], kl, acc[nt], 0, 0, 0);
        acc[nt] = __builtin_amdgcn_mfma_f32_16x16x32_bf16(qh[ks], kh, acc[nt], 0, 0, 0);
      }
    }
  }

  // ---- wave-local softmax; P -> split bf16 into wave-private LDS rows ----
  // C/D layout: row=(lane>>4)*4+reg, col=lane&15; each 16-lane group owns
  // 4 whole rows -> reduce via shfl_xor 1,2,4,8 (stays in-group).
#pragma unroll
  for (int r = 0; r < 4; ++r) {
    const int grow = 16 * w + rquad + r;
    float s[4];
#pragma unroll
    for (int nt = 0; nt < 4; ++nt) {
      const int col = 16 * nt + colb;
      s[nt] = (col < nrows) ? acc[nt][r] * 0.125f : -1e30f;
    }
    float m = fmaxf(fmaxf(s[0], s[1]), fmaxf(s[2], s[3]));
    m = fmaxf(m, __shfl_xor(m, 1));
    m = fmaxf(m, __shfl_xor(m, 2));
    m = fmaxf(m, __shfl_xor(m, 4));
    m = fmaxf(m, __shfl_xor(m, 8));
    float p[4];
    float lsum = 0.f;
#pragma unroll
    for (int nt = 0; nt < 4; ++nt) {
      p[nt] = __expf(s[nt] - m);
      lsum += p[nt];
    }
    lsum += __shfl_xor(lsum, 1);
    lsum += __shfl_xor(lsum, 2);
    lsum += __shfl_xor(lsum, 4);
    lsum += __shfl_xor(lsum, 8);
    const float inv = 1.f / lsum;
#pragma unroll
    for (int nt = 0; nt < 4; ++nt) {
      unsigned short hh, ll;
      split2(p[nt] * inv, hh, ll);
      Ph[grow * STRH + 16 * nt + colb] = hh;
      Pl[grow * STRH + 16 * nt + colb] = ll;
    }
  }
  // no barrier: wave w only re-reads rows 16w..16w+15, which it just wrote;
  // compiler-inserted s_waitcnt lgkmcnt orders the ds_write -> ds_read.

  // ---- P fragments back from LDS in A-frag layout ----
  short8 ph[2], pl[2];
#pragma unroll
  for (int ks = 0; ks < 2; ++ks) {
    ph[ks] = *(const short8*)&Ph[arow * STRH + ks * 32 + kofs];
    pl[ks] = *(const short8*)&Pl[arow * STRH + ks * 32 + kofs];
  }

  // ---- O = P V: V fragments gathered transposed from global ----
  f32x4 oacc[4];
#pragma unroll
  for (int i = 0; i < 4; ++i) oacc[i] = (f32x4){0.f, 0.f, 0.f, 0.f};
#pragma unroll
  for (int nt = 0; nt < 4; ++nt) {
    const float* vp = vg + base + 16 * nt + colb;  // column 16nt+colb
#pragma unroll
    for (int ks = 0; ks < 2; ++ks) {
      if (ks * 32 < nrows) {  // wave-uniform; k rows ks*32+kofs+j < nrows
        float vf[8];
#pragma unroll
        for (int j = 0; j < 8; ++j)
          vf[j] = vp[(size_t)(ks * 32 + kofs + j) * 64];
        short8 vh, vl;
        split8(vf, vh, vl);
        oacc[nt] = __builtin_amdgcn_mfma_f32_16x16x32_bf16(pl[ks], vh, oacc[nt], 0, 0, 0);
        oacc[nt] = __builtin_amdgcn_mfma_f32_16x16x32_bf16(ph[ks], vl, oacc[nt], 0, 0, 0);
        oacc[nt] = __builtin_amdgcn_mfma_f32_16x16x32_bf16(ph[ks], vh, oacc[nt], 0, 0, 0);
      }
    }
  }

  // ---- store (C/D: row=(lane>>4)*4+reg, col=lane&15) ----
  if (wvalid) {
#pragma unroll
    for (int nt = 0; nt < 4; ++nt) {
#pragma unroll
      for (int r = 0; r < 4; ++r) {
        const int row = 16 * w + rquad + r;
        if (row < nrows) {
          og[base + (size_t)row * 64 + 16 * nt + colb] = oacc[nt][r];
        }
      }
    }
  }
}

extern "C" void kernel_launch(void* const* d_in, const int* in_sizes, int n_in,
                              void* d_out, int out_size, void* d_ws, size_t ws_size,
                              hipStream_t stream) {
  const float* q = (const float*)d_in[0];
  const float* k = (const float*)d_in[1];
  const float* v = (const float*)d_in[2];
  float* o = (float*)d_out;

  const int N    = 4128;
  const int BH   = in_sizes[0] / (N * 64);  // 64
  const int nblk = (N + 63) / 64;           // 65
  const int rem  = N & 63;                  // 32

  bda_kernel<<<dim3(BH * nblk), dim3(256), 0, stream>>>(q, k, v, o, N, nblk, rem);
}